// Round 2
// baseline (422.953 us; speedup 1.0000x reference)
//
#include <hip/hip_runtime.h>
#include <hip/hip_bf16.h>

// CrossAttention: 3 heads, B=8, LQ=LK=1024, H=768.
// R9: gemm_gv pipelined properly: ring of 4 BK=32 slices, staged 3 ahead (counted
//     vmcnt(8)), and — the R8 fix — MFMA consumes REGISTER fragments prefetched one
//     slice earlier (ds_read issued before the barrier, latency absorbed by the
//     barrier wait + STAGE issue of the next iteration). Second-half A frags read
//     just-in-time under the first MFMA cluster. Heads merged into one N=2304 GEMM
//     pair (Mt/WvT already contiguous h-major): grid (32,9,2).
//     Other kernels unchanged.

typedef _Float16 f16;
typedef __attribute__((ext_vector_type(8))) _Float16 f16x8;
typedef __attribute__((ext_vector_type(4))) float f32x4;
typedef __attribute__((ext_vector_type(4))) short s16x4;

#define DI __device__ __forceinline__

DI short f2hs(float f){
  f16 h = (f16)f;                       // RNE
  return __builtin_bit_cast(short, h);
}
DI float hs2f(short s){
  return (float)__builtin_bit_cast(f16, s);
}

DI f32x4 mfma16(f16x8 a, f16x8 b, f32x4 c){
  return __builtin_amdgcn_mfma_f32_16x16x32_f16(a, b, c, 0, 0, 0);
}

#define GLL16(gp, lp) __builtin_amdgcn_global_load_lds( \
    (const __attribute__((address_space(1))) unsigned int*)(gp), \
    (__attribute__((address_space(3))) unsigned int*)(lp), 16, 0, 0)

// ---------------- elementwise f32 -> fp16, two tensors in one launch ----------------
__global__ void cvt2_f16_kernel(const float* __restrict__ a, const float* __restrict__ b,
                                short* __restrict__ oa, short* __restrict__ ob, int n4each){
  int i = blockIdx.x * blockDim.x + threadIdx.x;
  const float* in = (i < n4each) ? a : b;
  short* out = (i < n4each) ? oa : ob;
  int j = (i < n4each) ? i : i - n4each;
  f32x4 v = ((const f32x4*)in)[j];
  s16x4 o;
  o[0]=f2hs(v[0]); o[1]=f2hs(v[1]); o[2]=f2hs(v[2]); o[3]=f2hs(v[3]);
  ((s16x4*)out)[j] = o;
}

// ---------------- transpose+cvt Wv (3 heads 768x768) and Wp (2304x768) in one launch ----------------
__global__ void transpose2_kernel(const float* __restrict__ Wv, const float* __restrict__ Wp,
                                  short* __restrict__ WvT, short* __restrict__ WpT){
  __shared__ float tile[32][33];
  const float* in; short* out; int R, r0;
  if (blockIdx.z == 0){
    int hd = blockIdx.y / 24;
    in = Wv + (long)hd*768*768; out = WvT + (long)hd*768*768;
    R = 768; r0 = (blockIdx.y % 24) * 32;
  } else {
    in = Wp; out = WpT; R = 2304; r0 = blockIdx.y * 32;
  }
  int c0 = blockIdx.x * 32;
  int tx = threadIdx.x, ty = threadIdx.y;
  #pragma unroll
  for (int k=0;k<4;k++)
    tile[ty + k*8][tx] = in[(long)(r0 + ty + k*8) * 768 + c0 + tx];
  __syncthreads();
  #pragma unroll
  for (int k=0;k<4;k++)
    out[(long)(c0 + ty + k*8) * R + r0 + tx] = f2hs(tile[tx][ty + k*8]);
}

// ---------------- shared 128x128 GEMM core, BK=64 (two BK=32 LDS sub-buffers) ----------------
// As/Bs: [2][128][32] shorts = 16 KB each. 8 GLL16/wave per barrier pair.
DI void gemm_tile64(const short* __restrict__ A, const short* __restrict__ Bt, int K,
                    int m0, int n0, short* As, short* Bs, f32x4 (&acc)[4][4])
{
  const int tid = threadIdx.x, wave = tid>>6, lane = tid&63;
  const int wm = wave>>1, wn = wave&1;
  const int fl = lane&15, fq = lane>>4;
  const int srow = lane>>2, scol = (lane&3)*8;
  for (int kk=0; kk<K; kk+=64){
    __syncthreads();
    #pragma unroll
    for (int c=0;c<2;c++)
      #pragma unroll
      for (int r=0;r<2;r++){
        const int rb = r*64 + wave*16;
        GLL16(A  + (long)(m0+rb+srow)*K + kk + c*32 + scol, As + c*4096 + rb*32);
        GLL16(Bt + (long)(n0+rb+srow)*K + kk + c*32 + scol, Bs + c*4096 + rb*32);
      }
    __syncthreads();
    #pragma unroll
    for (int c=0;c<2;c++){
      f16x8 a[4];
      #pragma unroll
      for (int i=0;i<4;i++) a[i] = *(const f16x8*)(As + c*4096 + (wm*64+i*16+fl)*32 + fq*8);
      #pragma unroll
      for (int j=0;j<4;j++){
        f16x8 b = *(const f16x8*)(Bs + c*4096 + (wn*64+j*16+fl)*32 + fq*8);
        #pragma unroll
        for (int i=0;i<4;i++) acc[i][j] = mfma16(a[i], b, acc[i][j]);
      }
    }
  }
}

// ---------------- M = Wq * Wk^T per head, stored transposed for use as Bt ----------------
__global__ __launch_bounds__(256,2) void gemm_m_kernel(
    const short* __restrict__ WqH, const short* __restrict__ WkH, short* __restrict__ Mt)
{
  __shared__ short As[8192];
  __shared__ short Bs[8192];
  const int h = blockIdx.z;
  const int m0 = blockIdx.x*128, n0 = blockIdx.y*128;
  const int tid = threadIdx.x, wave = tid>>6, lane = tid&63;
  const int wm = wave>>1, wn = wave&1;
  const int fl = lane&15, fq = lane>>4;

  f32x4 vz = {0.f,0.f,0.f,0.f};
  f32x4 acc[4][4];
  #pragma unroll
  for (int i=0;i<4;i++)
    #pragma unroll
    for (int j=0;j<4;j++) acc[i][j] = vz;

  gemm_tile64(WqH + (long)h*768*768, WkH + (long)h*768*768, 768, m0, n0, As, Bs, acc);

  short* outp = Mt + (long)h*768*768;      // Mt[d'][d]
  #pragma unroll
  for (int j=0;j<4;j++){
    int col = n0 + wn*64 + j*16 + fl;      // d'
    #pragma unroll
    for (int i=0;i<4;i++){
      int row = m0 + wm*64 + i*16 + fq*4;  // d
      s16x4 pack;
      #pragma unroll
      for (int r=0;r<4;r++) pack[r] = f2hs(acc[i][j][r]);
      *(s16x4*)(outp + (long)col*768 + row) = pack;
    }
  }
}

// ---------------- w[h][d] = sum_e Wk[h][d][e] * bq[h][e]  (fp32 Wk, wave per row) ----------------
__global__ void vvec_kernel(const float* __restrict__ Wk, const float* __restrict__ bq,
                            float* __restrict__ w){
  const int h = blockIdx.x, chunk = blockIdx.y;   // grid (3,8)
  const int tid = threadIdx.x, wave = tid>>6, lane = tid&63;
  const float* bql = bq + h*768 + lane*12;
  float bv[12];
  #pragma unroll
  for (int e=0;e<12;e++) bv[e] = bql[e];
  for (int r = 0; r < 24; r++){
    int d = chunk*96 + r*4 + wave;
    const float* row = Wk + ((long)h*768 + d)*768 + lane*12;
    float s = 0.f;
    #pragma unroll
    for (int e=0;e<12;e++) s += row[e] * bv[e];
    s += __shfl_xor(s, 1);
    s += __shfl_xor(s, 2);
    s += __shfl_xor(s, 4);
    s += __shfl_xor(s, 8);
    s += __shfl_xor(s, 16);
    s += __shfl_xor(s, 32);
    if (lane == 0) w[h*768 + d] = s;
  }
}

// ---------------- R9: 256x256-tile register-prefetch pipelined GEMM for G' and V ----------------
// Single N=2304 GEMM per 'which' (heads merged; Mt/WvT are [h*768+n][k] contiguous).
// Ring of 4 BK=32 slices (128 KB LDS), staged 3 ahead; frags for slice s read at end
// of iteration s-1 (before barrier -> latency hidden); vmcnt(8) keeps 2 slices in
// flight. Slot x overwritten at iteration x+1, strictly after barrier(x) which all
// readers' drained ds_reads precede. asm "memory" on every wait/barrier pins ordering.
__global__ __launch_bounds__(512,2) void gemm_gv2_kernel(
    const short* __restrict__ t1b, const short* __restrict__ t2b,
    const short* __restrict__ Mt, const short* __restrict__ WvT,
    const float* __restrict__ wv, const float* __restrict__ bv,
    short* __restrict__ Gb, short* __restrict__ Vtb)
{
  __shared__ short As4[4][8192];   // [ring][256 rows][32 k] fp16, 64 KB
  __shared__ short Bs4[4][8192];   // 64 KB

  const int which = blockIdx.z;             // 0: G' = t1*M ; 1: V = t2*Wv
  const short* A  = which ? t2b : t1b;
  const short* Bt = which ? WvT : Mt;       // [2304][768]
  const int m0 = blockIdx.x*256, n0 = blockIdx.y*256;
  const int tid = threadIdx.x, wave = tid>>6, lane = tid&63;
  const int wm = wave>>2, wn = wave&3;      // 2x4 wave grid, per-wave 128x64
  const int fl = lane&15, fq = lane>>4;

  // staging lane decomposition: each GLL writes 16 rows x 32 k (1 KB).
  const int lr = lane>>2;                           // row within 16-row group
  const int ss = ((lane&3) ^ ((lane>>3)&3)) * 8;    // swizzled source k-offset (shorts)
  // fragment read swizzle: slot = fq ^ ((row>>1)&3); row = 16*c + fl -> lane-only.
  const int rs = (fq ^ ((fl>>1)&3)) * 8;

  const short* Agl = A  + (long)(m0+lr)*768 + ss;
  const short* Bgl = Bt + (long)(n0+lr)*768 + ss;

  f32x4 vz = {0.f,0.f,0.f,0.f};
  f32x4 acc[8][4];
  #pragma unroll
  for (int i=0;i<8;i++)
    #pragma unroll
    for (int j=0;j<4;j++) acc[i][j] = vz;

  auto STAGE = [&](int sl, int s){
    const int kk = s*32;
    #pragma unroll
    for (int g=0; g<2; g++){
      const int rb = g*128 + wave*16;
      GLL16(Agl + (long)rb*768 + kk, &As4[sl][rb*32]);
      GLL16(Bgl + (long)rb*768 + kk, &Bs4[sl][rb*32]);
    }
  };

  f16x8 a1[2][4], bb[2][4], a2[4];

  auto READN = [&](int nx, int sl){
    const short* Ab = &As4[sl][0];
    const short* Bb = &Bs4[sl][0];
    #pragma unroll
    for (int j=0;j<4;j++) bb[nx][j] = *(const f16x8*)(Bb + (wn*64 + j*16 + fl)*32 + rs);
    #pragma unroll
    for (int i=0;i<4;i++) a1[nx][i] = *(const f16x8*)(Ab + (wm*128 + i*16 + fl)*32 + rs);
  };

  // prologue: slices 0..2 staged; frags(0) in regs
  STAGE(0, 0);
  STAGE(1, 1);
  STAGE(2, 2);
  asm volatile("s_waitcnt vmcnt(8)" ::: "memory");   // slice 0 landed (own loads)
  asm volatile("s_barrier" ::: "memory");            // slice 0 landed block-wide
  READN(0, 0);

  // K = 768 -> 24 slices of 32
  #pragma unroll
  for (int s = 0; s < 24; ++s){
    const int cur = s&1, nxt = cur^1;
    if (s <= 20) STAGE((s+3)&3, s+3);
    if (s <= 20)      asm volatile("s_waitcnt vmcnt(8)" ::: "memory"); // slice s+1 landed
    else if (s == 21) asm volatile("s_waitcnt vmcnt(4)" ::: "memory"); // slice 22 landed
    else if (s == 22) asm volatile("s_waitcnt vmcnt(0)" ::: "memory"); // slice 23 landed
    // just-in-time second-half A frags; latency hidden under the mq0 MFMA cluster
    {
      const short* Ab = &As4[s&3][0];
      #pragma unroll
      for (int i=0;i<4;i++)
        a2[i] = *(const f16x8*)(Ab + (wm*128 + 64 + i*16 + fl)*32 + rs);
    }
    __builtin_amdgcn_s_setprio(1);
    #pragma unroll
    for (int j=0;j<4;j++)
      #pragma unroll
      for (int i=0;i<4;i++)
        acc[i][j] = mfma16(a1[cur][i], bb[cur][j], acc[i][j]);
    #pragma unroll
    for (int j=0;j<4;j++)
      #pragma unroll
      for (int i=0;i<4;i++)
        acc[4+i][j] = mfma16(a2[i], bb[cur][j], acc[4+i][j]);
    __builtin_amdgcn_s_setprio(0);
    asm volatile("s_barrier" ::: "memory");
    if (s < 23) READN(nxt, (s+1)&3);
  }

  const int hN = n0 / 768;             // block's head (n0 never straddles a head)
  const int e0 = n0 - hN*768;
  if (which == 0){
    short* outp = Gb + (long)hN*8192*768;
    #pragma unroll
    for (int j=0;j<4;j++){
      int cg  = n0 + wn*64 + j*16 + fl;       // global col (bias index)
      int col = e0 + wn*64 + j*16 + fl;       // within-head col
      float bb_ = wv[cg];
      #pragma unroll
      for (int i=0;i<8;i++){
        int row = m0 + wm*128 + (i/4)*64 + (i%4)*16 + fq*4;
        #pragma unroll
        for (int r=0;r<4;r++)
          outp[(long)(row+r)*768 + col] = f2hs(acc[i][j][r] + bb_);
      }
    }
  } else {
    const int bidx = m0 >> 10;       // 256-row block never crosses a batch boundary
    const int lk0  = m0 & 1023;
    short* outp = Vtb + (long)(hN*8 + bidx)*768*1024;
    #pragma unroll
    for (int j=0;j<4;j++){
      int cg = n0 + wn*64 + j*16 + fl;
      int e  = e0 + wn*64 + j*16 + fl;
      float bb_ = bv[cg];
      #pragma unroll
      for (int i=0;i<8;i++){
        int lk = lk0 + wm*128 + (i/4)*64 + (i%4)*16 + fq*4;
        s16x4 pack;
        #pragma unroll
        for (int r=0;r<4;r++) pack[r] = f2hs(acc[i][j][r] + bb_);
        *(s16x4*)(outp + (long)e*1024 + lk) = pack;
      }
    }
  }
}

// ---------------- attention stage 1: S = G'*t2^T, tile-local exp ----------------
// Flat grid 1536, XCD-swizzled: 3 hb per XCD (G+t2 slice = 3MB fits 4MB XCD L2).
__global__ __launch_bounds__(256,2) void qk_exp_kernel(
    const short* __restrict__ Gb, const short* __restrict__ t2b,
    short* __restrict__ P, float* __restrict__ Mx, float* __restrict__ Lx)
{
  __shared__ short As[8192];
  __shared__ short Bs[8192];
  __shared__ float red0[2][2][64];   // [wn][wm][row64] tile-local max
  __shared__ float red1[2][2][64];   // [wn][wm][row64] tile-local sum
  const int id = blockIdx.x;
  const int xcd = id & 7, s_ = id >> 3;          // s_ in 0..191
  const int hb = xcd*3 + (s_ >> 6);
  const int inner = s_ & 63;
  const int qt = inner & 7, ct = inner >> 3;
  const int h = hb >> 3, b = hb & 7;
  const int tid = threadIdx.x, wave = tid>>6, lane = tid&63;
  const int wm = wave>>1, wn = wave&1;
  const int fl = lane&15, fq = lane>>4;
  const short* Abase = Gb + ((long)h*8192 + b*1024)*768;
  const short* Bbase = t2b + (long)b*1024*768;

  f32x4 vz = {0.f,0.f,0.f,0.f};
  f32x4 acc[4][4];
  #pragma unroll
  for (int i=0;i<4;i++)
    #pragma unroll
    for (int j=0;j<4;j++) acc[i][j] = vz;

  gemm_tile64(Abase, Bbase, 768, qt*128, ct*128, As, Bs, acc);

  // tile-local row max over this wave's 64 cols, then across wn pair via LDS
  float mt[4][4];
  #pragma unroll
  for (int i=0;i<4;i++)
    #pragma unroll
    for (int r=0;r<4;r++){
      float m = acc[i][0][r];
      #pragma unroll
      for (int j=1;j<4;j++) m = fmaxf(m, acc[i][j][r]);
      m = fmaxf(m, __shfl_xor(m, 1));
      m = fmaxf(m, __shfl_xor(m, 2));
      m = fmaxf(m, __shfl_xor(m, 4));
      m = fmaxf(m, __shfl_xor(m, 8));
      mt[i][r] = m;
      if (fl == 0) red0[wn][wm][i*16 + fq*4 + r] = m;
    }
  __syncthreads();
  #pragma unroll
  for (int i=0;i<4;i++)
    #pragma unroll
    for (int r=0;r<4;r++)
      mt[i][r] = fmaxf(red0[0][wm][i*16 + fq*4 + r], red0[1][wm][i*16 + fq*4 + r]);

  // exp + tile-local sums
  #pragma unroll
  for (int i=0;i<4;i++)
    #pragma unroll
    for (int r=0;r<4;r++){
      float s = 0.f;
      #pragma unroll
      for (int j=0;j<4;j++){
        float p = __expf(acc[i][j][r] - mt[i][r]);
        acc[i][j][r] = p;
        s += p;
      }
      s += __shfl_xor(s, 1);
      s += __shfl_xor(s, 2);
      s += __shfl_xor(s, 4);
      s += __shfl_xor(s, 8);
      if (fl == 0) red1[wn][wm][i*16 + fq*4 + r] = s;
    }
  __syncthreads();

  // store P_u (fp16) and per-(row, ctile) aux
  #pragma unroll
  for (int j=0;j<4;j++){
    int c = ct*128 + wn*64 + j*16 + fl;
    #pragma unroll
    for (int i=0;i<4;i++){
      int q = qt*128 + wm*64 + i*16 + fq*4;
      #pragma unroll
      for (int r=0;r<4;r++)
        P[((long)hb*1024 + q + r)*1024 + c] = f2hs(acc[i][j][r]);
    }
  }
  if (fl == 0 && wn == 0){
    long aux = ((long)(hb*8 + ct))*1024 + qt*128;
    #pragma unroll
    for (int i=0;i<4;i++)
      #pragma unroll
      for (int r=0;r<4;r++){
        int row = wm*64 + i*16 + fq*4 + r;
        Mx[aux + row] = mt[i][r];
        Lx[aux + row] = red1[0][wm][row & 63] + red1[1][wm][row & 63];
      }
  }
}

// ---------------- attention stage 2: ctx = (f .* P_u) @ V^T, relu, store multi ----------------
// Flat grid 1152, XCD-swizzled. Softmax factors computed fp32 in the prologue (no Sc buffer).
__global__ __launch_bounds__(256,2) void pv_kernel(
    const short* __restrict__ P, const short* __restrict__ Vtb,
    const float* __restrict__ Mx, const float* __restrict__ Lx, short* __restrict__ multi)
{
  __shared__ short As[8192];
  __shared__ short Bs[8192];
  __shared__ float scl[8][128];      // [ct][qrow] softmax factor
  const int id = blockIdx.x;
  const int xcd = id & 7, s_ = id >> 3;          // s_ in 0..143
  const int hb = xcd*3 + s_/48;
  const int inner = s_ % 48;
  const int qt = inner & 7, et = inner >> 3;     // et 0..5
  const int h = hb >> 3, b = hb & 7;
  const int tid = threadIdx.x, wave = tid>>6, lane = tid&63;
  const int wm = wave>>1, wn = wave&1;
  const int fl = lane&15, fq = lane>>4;
  const int srow = lane>>2, scol = (lane&3)*8;
  const short* Abase = P + (long)hb*1024*1024 + (long)(qt*128)*1024;
  const short* Bbase = Vtb + (long)hb*768*1024 + (long)(et*128)*1024;

  // prologue: factors f[ct][q] = exp(m_t - m_g)/l_g for this block's 128 q-rows
  if (tid < 128){
    long a0 = ((long)(hb*8))*1024 + qt*128 + tid;
    float m[8], l[8];
    #pragma unroll
    for (int t=0;t<8;t++){ m[t] = Mx[a0 + t*1024]; l[t] = Lx[a0 + t*1024]; }
    float mg = m[0];
    #pragma unroll
    for (int t=1;t<8;t++) mg = fmaxf(mg, m[t]);
    float lg = 0.f;
    #pragma unroll
    for (int t=0;t<8;t++) lg += l[t] * __expf(m[t] - mg);
    float inv = 1.0f / lg;
    #pragma unroll
    for (int t=0;t<8;t++) scl[t][tid] = __expf(m[t] - mg) * inv;
  }
  __syncthreads();

  f32x4 vz = {0.f,0.f,0.f,0.f};
  f32x4 acc[4][4];
  #pragma unroll
  for (int i=0;i<4;i++)
    #pragma unroll
    for (int j=0;j<4;j++) acc[i][j] = vz;

  for (int ct=0; ct<8; ct++){
    f16 s[4];
    #pragma unroll
    for (int i=0;i<4;i++) s[i] = (f16)scl[ct][wm*64 + i*16 + fl];
    #pragma unroll
    for (int t=0;t<2;t++){
      const int kk = ct*128 + t*64;
      __syncthreads();
      #pragma unroll
      for (int c=0;c<2;c++)
        #pragma unroll
        for (int r=0;r<2;r++){
          const int rb = r*64 + wave*16;
          GLL16(Abase + (long)(rb+srow)*1024 + kk + c*32 + scol, As + c*4096 + rb*32);
          GLL16(Bbase + (long)(rb+srow)*1024 + kk + c*32 + scol, Bs + c*4096 + rb*32);
        }
      __syncthreads();
      #pragma unroll
      for (int c=0;c<2;c++){
        f16x8 a[4];
        #pragma unroll
        for (int i=0;i<4;i++){
          f16x8 av = *(const f16x8*)(As + c*4096 + (wm*64+i*16+fl)*32 + fq*8);
          f16x8 sv;
          #pragma unroll
          for (int e=0;e<8;e++) sv[e] = s[i];
          a[i] = av * sv;
        }
        #pragma unroll
        for (int j=0;j<4;j++){
          f16x8 bvv = *(const f16x8*)(Bs + c*4096 + (wn*64+j*16+fl)*32 + fq*8);
          #pragma unroll
          for (int i=0;i<4;i++) acc[i][j] = mfma16(a[i], bvv, acc[i][j]);
        }
      }
    }
  }

  short* mp = multi + (long)(b*1024 + qt*128)*2304 + h*768 + et*128;
  #pragma unroll
  for (int j=0;j<4;j++){
    int e = wn*64 + j*16 + fl;
    #pragma unroll
    for (int i=0;i<4;i++){
      int q = wm*64 + i*16 + fq*4;
      #pragma unroll
      for (int r=0;r<4;r++)
        mp[(long)(q+r)*2304 + e] = f2hs(fmaxf(acc[i][j][r], 0.f));
    }
  }
}

// ---------------- final projection: relu(multi)[8192,2304] @ Wp + bp -> fp32 out ----------------
__global__ __launch_bounds__(256,2) void gemm_out_kernel(
    const short* __restrict__ A, const short* __restrict__ Bt,
    const float* __restrict__ bias, float* __restrict__ out)
{
  __shared__ short As[8192];
  __shared__ short Bs[8192];
  const int m0 = blockIdx.x*128, n0 = blockIdx.y*128;
  const int tid = threadIdx.x, wave = tid>>6, lane = tid&63;
  const int wm = wave>>1, wn = wave&1;
  const int fl = lane&15, fq = lane>>4;

  f32x4 vz = {0.f,0.f,0.f,0.f};
  f32x4 acc[4][4];
  #pragma unroll
  for (int i=0;i<4;i++)
    #pragma unroll
    for (int j=0;j<4;j++) acc[i][j] = vz;

  gemm_tile64(A, Bt, 2304, m0, n0, As, Bs, acc);

  #pragma unroll
  for (int j=0;j<4;j++){
    int col = n0 + wn*64 + j*16 + fl;
    float bb = bias[col];
    #pragma unroll
    for (int i=0;i<4;i++){
      int row = m0 + wm*64 + i*16 + fq*4;
      #pragma unroll
      for (int r=0;r<4;r++)
        out[(long)(row+r)*768 + col] = acc[i][j][r] + bb;
    }
  }
}

extern "C" void kernel_launch(void* const* d_in, const int* in_sizes, int n_in,
                              void* d_out, int out_size, void* d_ws, size_t ws_size,
                              hipStream_t stream)
{
  const float* t1 = (const float*)d_in[0];
  const float* t2 = (const float*)d_in[1];
  const float* Wq = (const float*)d_in[2];
  const float* bq = (const float*)d_in[3];
  const float* Wk = (const float*)d_in[4];
  // d_in[5] = bk cancels in softmax (row-constant)
  const float* Wv = (const float*)d_in[6];
  const float* bv = (const float*)d_in[7];
  const float* Wp = (const float*)d_in[8];
  const float* bp = (const float*)d_in[9];
  float* out = (float*)d_out;

  char* ws = (char*)d_ws;
  size_t off = 0;
  auto carve = [&](size_t bytes){ void* p = ws + off; off += (bytes + 255) & ~(size_t)255; return p; };
  short* t1b = (short*)carve(8L*1024*768*2);
  short* t2b = (short*)carve(8L*1024*768*2);
  short* WqH = (short*)carve(3L*768*768*2);       // plain fp16 [h][in][out]
  short* WkH = (short*)carve(3L*768*768*2);
  short* WvT = (short*)carve(3L*768*768*2);
  short* WpT = (short*)carve(768L*2304*2);
  short* Mt  = (short*)carve(3L*768*768*2);       // (Wq Wk^T)^T per head, fp16 [h*768+d'][d]
  short* Gb  = (short*)carve(3L*8192*768*2);      // G' = t1*M + w
  short* Vtb = (short*)carve(3L*8*768*1024*2);    // [hb][e][lk]
  short* Pb  = (short*)carve(24L*1024*1024*2);    // [hb][q][c]
  float* Mx  = (float*)carve(24L*8*1024*4);       // [hb*8+ct][q]
  float* Lx  = (float*)carve(24L*8*1024*4);
  float* wvb = (float*)carve(3L*768*4);           // w = Wk bq
  short* multib = Gb;   // alias: Gb dead after qk_exp; multi written by pv, read by gemm_out

  cvt2_f16_kernel<<<12288, 256, 0, stream>>>(t1, t2, t1b, t2b, 1572864);
  cvt2_f16_kernel<<<3456, 256, 0, stream>>>(Wq, Wk, WqH, WkH, 442368);
  transpose2_kernel<<<dim3(24,72,2), dim3(32,8), 0, stream>>>(Wv, Wp, WvT, WpT);
  vvec_kernel<<<dim3(3,8), 256, 0, stream>>>(Wk, bq, wvb);
  gemm_m_kernel<<<dim3(6,6,3), 256, 0, stream>>>(WqH, WkH, Mt);
  gemm_gv2_kernel<<<dim3(32,9,2), 512, 0, stream>>>(t1b, t2b, Mt, WvT, wvb, bv, Gb, Vtb);
  qk_exp_kernel<<<1536, 256, 0, stream>>>(Gb, t2b, Pb, Mx, Lx);
  pv_kernel<<<1152, 256, 0, stream>>>(Pb, Vtb, Mx, Lx, multib);
  gemm_out_kernel<<<dim3(64,6,1), 256, 0, stream>>>(multib, WpT, bp, out);
}

// Round 3
// 395.078 us; speedup vs baseline: 1.0706x; 1.0706x over previous
//
#include <hip/hip_runtime.h>
#include <hip/hip_bf16.h>

// CrossAttention: 3 heads, B=8, LQ=LK=1024, H=768.
// R10: pure revert of the G/V GEMM to the R7-proven 128x128 BK=64 form (82 us,
//      2.75 blocks/CU cross-block overlap). The 256x256 deep-pipeline variants
//      (R8/R9) both landed at 91-94 us: 1 block/CU + 576-block grid quantization
//      (33% slack) + first-pass L3 latency exceeding the 2-slice prefetch budget.
//      Lesson recorded: on short-K (768) GEMMs here, co-resident-block overlap
//      beats intra-block pipelining. Everything else unchanged from R7.

typedef _Float16 f16;
typedef __attribute__((ext_vector_type(8))) _Float16 f16x8;
typedef __attribute__((ext_vector_type(4))) float f32x4;
typedef __attribute__((ext_vector_type(4))) short s16x4;

#define DI __device__ __forceinline__

DI short f2hs(float f){
  f16 h = (f16)f;                       // RNE
  return __builtin_bit_cast(short, h);
}
DI float hs2f(short s){
  return (float)__builtin_bit_cast(f16, s);
}

DI f32x4 mfma16(f16x8 a, f16x8 b, f32x4 c){
  return __builtin_amdgcn_mfma_f32_16x16x32_f16(a, b, c, 0, 0, 0);
}

#define GLL16(gp, lp) __builtin_amdgcn_global_load_lds( \
    (const __attribute__((address_space(1))) unsigned int*)(gp), \
    (__attribute__((address_space(3))) unsigned int*)(lp), 16, 0, 0)

// ---------------- elementwise f32 -> fp16, two tensors in one launch ----------------
__global__ void cvt2_f16_kernel(const float* __restrict__ a, const float* __restrict__ b,
                                short* __restrict__ oa, short* __restrict__ ob, int n4each){
  int i = blockIdx.x * blockDim.x + threadIdx.x;
  const float* in = (i < n4each) ? a : b;
  short* out = (i < n4each) ? oa : ob;
  int j = (i < n4each) ? i : i - n4each;
  f32x4 v = ((const f32x4*)in)[j];
  s16x4 o;
  o[0]=f2hs(v[0]); o[1]=f2hs(v[1]); o[2]=f2hs(v[2]); o[3]=f2hs(v[3]);
  ((s16x4*)out)[j] = o;
}

// ---------------- transpose+cvt Wv (3 heads 768x768) and Wp (2304x768) in one launch ----------------
__global__ void transpose2_kernel(const float* __restrict__ Wv, const float* __restrict__ Wp,
                                  short* __restrict__ WvT, short* __restrict__ WpT){
  __shared__ float tile[32][33];
  const float* in; short* out; int R, r0;
  if (blockIdx.z == 0){
    int hd = blockIdx.y / 24;
    in = Wv + (long)hd*768*768; out = WvT + (long)hd*768*768;
    R = 768; r0 = (blockIdx.y % 24) * 32;
  } else {
    in = Wp; out = WpT; R = 2304; r0 = blockIdx.y * 32;
  }
  int c0 = blockIdx.x * 32;
  int tx = threadIdx.x, ty = threadIdx.y;
  #pragma unroll
  for (int k=0;k<4;k++)
    tile[ty + k*8][tx] = in[(long)(r0 + ty + k*8) * 768 + c0 + tx];
  __syncthreads();
  #pragma unroll
  for (int k=0;k<4;k++)
    out[(long)(c0 + ty + k*8) * R + r0 + tx] = f2hs(tile[tx][ty + k*8]);
}

// ---------------- shared 128x128 GEMM core, BK=64 (two BK=32 LDS sub-buffers) ----------------
// As/Bs: [2][128][32] shorts = 16 KB each. 8 GLL16/wave per barrier pair.
DI void gemm_tile64(const short* __restrict__ A, const short* __restrict__ Bt, int K,
                    int m0, int n0, short* As, short* Bs, f32x4 (&acc)[4][4])
{
  const int tid = threadIdx.x, wave = tid>>6, lane = tid&63;
  const int wm = wave>>1, wn = wave&1;
  const int fl = lane&15, fq = lane>>4;
  const int srow = lane>>2, scol = (lane&3)*8;
  for (int kk=0; kk<K; kk+=64){
    __syncthreads();
    #pragma unroll
    for (int c=0;c<2;c++)
      #pragma unroll
      for (int r=0;r<2;r++){
        const int rb = r*64 + wave*16;
        GLL16(A  + (long)(m0+rb+srow)*K + kk + c*32 + scol, As + c*4096 + rb*32);
        GLL16(Bt + (long)(n0+rb+srow)*K + kk + c*32 + scol, Bs + c*4096 + rb*32);
      }
    __syncthreads();
    #pragma unroll
    for (int c=0;c<2;c++){
      f16x8 a[4];
      #pragma unroll
      for (int i=0;i<4;i++) a[i] = *(const f16x8*)(As + c*4096 + (wm*64+i*16+fl)*32 + fq*8);
      #pragma unroll
      for (int j=0;j<4;j++){
        f16x8 b = *(const f16x8*)(Bs + c*4096 + (wn*64+j*16+fl)*32 + fq*8);
        #pragma unroll
        for (int i=0;i<4;i++) acc[i][j] = mfma16(a[i], b, acc[i][j]);
      }
    }
  }
}

// ---------------- M = Wq * Wk^T per head, stored transposed for use as Bt ----------------
__global__ __launch_bounds__(256,2) void gemm_m_kernel(
    const short* __restrict__ WqH, const short* __restrict__ WkH, short* __restrict__ Mt)
{
  __shared__ short As[8192];
  __shared__ short Bs[8192];
  const int h = blockIdx.z;
  const int m0 = blockIdx.x*128, n0 = blockIdx.y*128;
  const int tid = threadIdx.x, wave = tid>>6, lane = tid&63;
  const int wm = wave>>1, wn = wave&1;
  const int fl = lane&15, fq = lane>>4;

  f32x4 vz = {0.f,0.f,0.f,0.f};
  f32x4 acc[4][4];
  #pragma unroll
  for (int i=0;i<4;i++)
    #pragma unroll
    for (int j=0;j<4;j++) acc[i][j] = vz;

  gemm_tile64(WqH + (long)h*768*768, WkH + (long)h*768*768, 768, m0, n0, As, Bs, acc);

  short* outp = Mt + (long)h*768*768;      // Mt[d'][d]
  #pragma unroll
  for (int j=0;j<4;j++){
    int col = n0 + wn*64 + j*16 + fl;      // d'
    #pragma unroll
    for (int i=0;i<4;i++){
      int row = m0 + wm*64 + i*16 + fq*4;  // d
      s16x4 pack;
      #pragma unroll
      for (int r=0;r<4;r++) pack[r] = f2hs(acc[i][j][r]);
      *(s16x4*)(outp + (long)col*768 + row) = pack;
    }
  }
}

// ---------------- w[h][d] = sum_e Wk[h][d][e] * bq[h][e]  (fp32 Wk, wave per row) ----------------
__global__ void vvec_kernel(const float* __restrict__ Wk, const float* __restrict__ bq,
                            float* __restrict__ w){
  const int h = blockIdx.x, chunk = blockIdx.y;   // grid (3,8)
  const int tid = threadIdx.x, wave = tid>>6, lane = tid&63;
  const float* bql = bq + h*768 + lane*12;
  float bv[12];
  #pragma unroll
  for (int e=0;e<12;e++) bv[e] = bql[e];
  for (int r = 0; r < 24; r++){
    int d = chunk*96 + r*4 + wave;
    const float* row = Wk + ((long)h*768 + d)*768 + lane*12;
    float s = 0.f;
    #pragma unroll
    for (int e=0;e<12;e++) s += row[e] * bv[e];
    s += __shfl_xor(s, 1);
    s += __shfl_xor(s, 2);
    s += __shfl_xor(s, 4);
    s += __shfl_xor(s, 8);
    s += __shfl_xor(s, 16);
    s += __shfl_xor(s, 32);
    if (lane == 0) w[h*768 + d] = s;
  }
}

// ---------------- G' = t1*M + w (col bias) and V = t2*Wv + bv (transposed store) ----------------
__global__ __launch_bounds__(256,2) void gemm_gv_kernel(
    const short* __restrict__ t1b, const short* __restrict__ t2b,
    const short* __restrict__ Mt, const short* __restrict__ WvT,
    const float* __restrict__ wv, const float* __restrict__ bv,
    short* __restrict__ Gb, short* __restrict__ Vtb)
{
  __shared__ short As[8192];
  __shared__ short Bs[8192];
  const int z = blockIdx.z;                 // 0..5
  const int h = z % 3, which = z / 3;
  const short* A  = (which==0) ? t1b : t2b;
  const short* Bt = ((which==0)?Mt:WvT) + (long)h*768*768;
  const int m0 = blockIdx.x*128, n0 = blockIdx.y*128;
  const int tid = threadIdx.x, wave = tid>>6, lane = tid&63;
  const int wm = wave>>1, wn = wave&1;
  const int fl = lane&15, fq = lane>>4;

  f32x4 vz = {0.f,0.f,0.f,0.f};
  f32x4 acc[4][4];
  #pragma unroll
  for (int i=0;i<4;i++)
    #pragma unroll
    for (int j=0;j<4;j++) acc[i][j] = vz;

  gemm_tile64(A, Bt, 768, m0, n0, As, Bs, acc);

  if (which == 0){
    const float* bias = wv + h*768;
    short* outp = Gb + (long)h*8192*768;
    #pragma unroll
    for (int j=0;j<4;j++){
      int col = n0 + wn*64 + j*16 + fl;
      float bb = bias[col];
      #pragma unroll
      for (int i=0;i<4;i++){
        int row = m0 + wm*64 + i*16 + fq*4;
        #pragma unroll
        for (int r=0;r<4;r++)
          outp[(long)(row+r)*768 + col] = f2hs(acc[i][j][r] + bb);
      }
    }
  } else {
    const float* bias = bv + h*768;
    const int bidx = m0 >> 10;       // 128-row block never crosses a batch boundary
    const int lk0  = m0 & 1023;
    short* outp = Vtb + (long)(h*8 + bidx)*768*1024;
    #pragma unroll
    for (int j=0;j<4;j++){
      int e = n0 + wn*64 + j*16 + fl;
      float bb = bias[e];
      #pragma unroll
      for (int i=0;i<4;i++){
        int lk = lk0 + wm*64 + i*16 + fq*4;
        s16x4 pack;
        #pragma unroll
        for (int r=0;r<4;r++) pack[r] = f2hs(acc[i][j][r] + bb);
        *(s16x4*)(outp + (long)e*1024 + lk) = pack;
      }
    }
  }
}

// ---------------- attention stage 1: S = G'*t2^T, tile-local exp ----------------
// Flat grid 1536, XCD-swizzled: 3 hb per XCD (G+t2 slice = 3MB fits 4MB XCD L2).
__global__ __launch_bounds__(256,2) void qk_exp_kernel(
    const short* __restrict__ Gb, const short* __restrict__ t2b,
    short* __restrict__ P, float* __restrict__ Mx, float* __restrict__ Lx)
{
  __shared__ short As[8192];
  __shared__ short Bs[8192];
  __shared__ float red0[2][2][64];   // [wn][wm][row64] tile-local max
  __shared__ float red1[2][2][64];   // [wn][wm][row64] tile-local sum
  const int id = blockIdx.x;
  const int xcd = id & 7, s_ = id >> 3;          // s_ in 0..191
  const int hb = xcd*3 + (s_ >> 6);
  const int inner = s_ & 63;
  const int qt = inner & 7, ct = inner >> 3;
  const int h = hb >> 3, b = hb & 7;
  const int tid = threadIdx.x, wave = tid>>6, lane = tid&63;
  const int wm = wave>>1, wn = wave&1;
  const int fl = lane&15, fq = lane>>4;
  const short* Abase = Gb + ((long)h*8192 + b*1024)*768;
  const short* Bbase = t2b + (long)b*1024*768;

  f32x4 vz = {0.f,0.f,0.f,0.f};
  f32x4 acc[4][4];
  #pragma unroll
  for (int i=0;i<4;i++)
    #pragma unroll
    for (int j=0;j<4;j++) acc[i][j] = vz;

  gemm_tile64(Abase, Bbase, 768, qt*128, ct*128, As, Bs, acc);

  // tile-local row max over this wave's 64 cols, then across wn pair via LDS
  float mt[4][4];
  #pragma unroll
  for (int i=0;i<4;i++)
    #pragma unroll
    for (int r=0;r<4;r++){
      float m = acc[i][0][r];
      #pragma unroll
      for (int j=1;j<4;j++) m = fmaxf(m, acc[i][j][r]);
      m = fmaxf(m, __shfl_xor(m, 1));
      m = fmaxf(m, __shfl_xor(m, 2));
      m = fmaxf(m, __shfl_xor(m, 4));
      m = fmaxf(m, __shfl_xor(m, 8));
      mt[i][r] = m;
      if (fl == 0) red0[wn][wm][i*16 + fq*4 + r] = m;
    }
  __syncthreads();
  #pragma unroll
  for (int i=0;i<4;i++)
    #pragma unroll
    for (int r=0;r<4;r++)
      mt[i][r] = fmaxf(red0[0][wm][i*16 + fq*4 + r], red0[1][wm][i*16 + fq*4 + r]);

  // exp + tile-local sums
  #pragma unroll
  for (int i=0;i<4;i++)
    #pragma unroll
    for (int r=0;r<4;r++){
      float s = 0.f;
      #pragma unroll
      for (int j=0;j<4;j++){
        float p = __expf(acc[i][j][r] - mt[i][r]);
        acc[i][j][r] = p;
        s += p;
      }
      s += __shfl_xor(s, 1);
      s += __shfl_xor(s, 2);
      s += __shfl_xor(s, 4);
      s += __shfl_xor(s, 8);
      if (fl == 0) red1[wn][wm][i*16 + fq*4 + r] = s;
    }
  __syncthreads();

  // store P_u (fp16) and per-(row, ctile) aux
  #pragma unroll
  for (int j=0;j<4;j++){
    int c = ct*128 + wn*64 + j*16 + fl;
    #pragma unroll
    for (int i=0;i<4;i++){
      int q = qt*128 + wm*64 + i*16 + fq*4;
      #pragma unroll
      for (int r=0;r<4;r++)
        P[((long)hb*1024 + q + r)*1024 + c] = f2hs(acc[i][j][r]);
    }
  }
  if (fl == 0 && wn == 0){
    long aux = ((long)(hb*8 + ct))*1024 + qt*128;
    #pragma unroll
    for (int i=0;i<4;i++)
      #pragma unroll
      for (int r=0;r<4;r++){
        int row = wm*64 + i*16 + fq*4 + r;
        Mx[aux + row] = mt[i][r];
        Lx[aux + row] = red1[0][wm][row & 63] + red1[1][wm][row & 63];
      }
  }
}

// ---------------- attention stage 2: ctx = (f .* P_u) @ V^T, relu, store multi ----------------
// Flat grid 1152, XCD-swizzled. Softmax factors computed fp32 in the prologue (no Sc buffer).
__global__ __launch_bounds__(256,2) void pv_kernel(
    const short* __restrict__ P, const short* __restrict__ Vtb,
    const float* __restrict__ Mx, const float* __restrict__ Lx, short* __restrict__ multi)
{
  __shared__ short As[8192];
  __shared__ short Bs[8192];
  __shared__ float scl[8][128];      // [ct][qrow] softmax factor
  const int id = blockIdx.x;
  const int xcd = id & 7, s_ = id >> 3;          // s_ in 0..143
  const int hb = xcd*3 + s_/48;
  const int inner = s_ % 48;
  const int qt = inner & 7, et = inner >> 3;     // et 0..5
  const int h = hb >> 3, b = hb & 7;
  const int tid = threadIdx.x, wave = tid>>6, lane = tid&63;
  const int wm = wave>>1, wn = wave&1;
  const int fl = lane&15, fq = lane>>4;
  const int srow = lane>>2, scol = (lane&3)*8;
  const short* Abase = P + (long)hb*1024*1024 + (long)(qt*128)*1024;
  const short* Bbase = Vtb + (long)hb*768*1024 + (long)(et*128)*1024;

  // prologue: factors f[ct][q] = exp(m_t - m_g)/l_g for this block's 128 q-rows
  if (tid < 128){
    long a0 = ((long)(hb*8))*1024 + qt*128 + tid;
    float m[8], l[8];
    #pragma unroll
    for (int t=0;t<8;t++){ m[t] = Mx[a0 + t*1024]; l[t] = Lx[a0 + t*1024]; }
    float mg = m[0];
    #pragma unroll
    for (int t=1;t<8;t++) mg = fmaxf(mg, m[t]);
    float lg = 0.f;
    #pragma unroll
    for (int t=0;t<8;t++) lg += l[t] * __expf(m[t] - mg);
    float inv = 1.0f / lg;
    #pragma unroll
    for (int t=0;t<8;t++) scl[t][tid] = __expf(m[t] - mg) * inv;
  }
  __syncthreads();

  f32x4 vz = {0.f,0.f,0.f,0.f};
  f32x4 acc[4][4];
  #pragma unroll
  for (int i=0;i<4;i++)
    #pragma unroll
    for (int j=0;j<4;j++) acc[i][j] = vz;

  for (int ct=0; ct<8; ct++){
    f16 s[4];
    #pragma unroll
    for (int i=0;i<4;i++) s[i] = (f16)scl[ct][wm*64 + i*16 + fl];
    #pragma unroll
    for (int t=0;t<2;t++){
      const int kk = ct*128 + t*64;
      __syncthreads();
      #pragma unroll
      for (int c=0;c<2;c++)
        #pragma unroll
        for (int r=0;r<2;r++){
          const int rb = r*64 + wave*16;
          GLL16(Abase + (long)(rb+srow)*1024 + kk + c*32 + scol, As + c*4096 + rb*32);
          GLL16(Bbase + (long)(rb+srow)*1024 + kk + c*32 + scol, Bs + c*4096 + rb*32);
        }
      __syncthreads();
      #pragma unroll
      for (int c=0;c<2;c++){
        f16x8 a[4];
        #pragma unroll
        for (int i=0;i<4;i++){
          f16x8 av = *(const f16x8*)(As + c*4096 + (wm*64+i*16+fl)*32 + fq*8);
          f16x8 sv;
          #pragma unroll
          for (int e=0;e<8;e++) sv[e] = s[i];
          a[i] = av * sv;
        }
        #pragma unroll
        for (int j=0;j<4;j++){
          f16x8 bvv = *(const f16x8*)(Bs + c*4096 + (wn*64+j*16+fl)*32 + fq*8);
          #pragma unroll
          for (int i=0;i<4;i++) acc[i][j] = mfma16(a[i], bvv, acc[i][j]);
        }
      }
    }
  }

  short* mp = multi + (long)(b*1024 + qt*128)*2304 + h*768 + et*128;
  #pragma unroll
  for (int j=0;j<4;j++){
    int e = wn*64 + j*16 + fl;
    #pragma unroll
    for (int i=0;i<4;i++){
      int q = wm*64 + i*16 + fq*4;
      #pragma unroll
      for (int r=0;r<4;r++)
        mp[(long)(q+r)*2304 + e] = f2hs(fmaxf(acc[i][j][r], 0.f));
    }
  }
}

// ---------------- final projection: relu(multi)[8192,2304] @ Wp + bp -> fp32 out ----------------
__global__ __launch_bounds__(256,2) void gemm_out_kernel(
    const short* __restrict__ A, const short* __restrict__ Bt,
    const float* __restrict__ bias, float* __restrict__ out)
{
  __shared__ short As[8192];
  __shared__ short Bs[8192];
  const int m0 = blockIdx.x*128, n0 = blockIdx.y*128;
  const int tid = threadIdx.x, wave = tid>>6, lane = tid&63;
  const int wm = wave>>1, wn = wave&1;
  const int fl = lane&15, fq = lane>>4;

  f32x4 vz = {0.f,0.f,0.f,0.f};
  f32x4 acc[4][4];
  #pragma unroll
  for (int i=0;i<4;i++)
    #pragma unroll
    for (int j=0;j<4;j++) acc[i][j] = vz;

  gemm_tile64(A, Bt, 2304, m0, n0, As, Bs, acc);

  #pragma unroll
  for (int j=0;j<4;j++){
    int col = n0 + wn*64 + j*16 + fl;
    float bb = bias[col];
    #pragma unroll
    for (int i=0;i<4;i++){
      int row = m0 + wm*64 + i*16 + fq*4;
      #pragma unroll
      for (int r=0;r<4;r++)
        out[(long)(row+r)*768 + col] = acc[i][j][r] + bb;
    }
  }
}

extern "C" void kernel_launch(void* const* d_in, const int* in_sizes, int n_in,
                              void* d_out, int out_size, void* d_ws, size_t ws_size,
                              hipStream_t stream)
{
  const float* t1 = (const float*)d_in[0];
  const float* t2 = (const float*)d_in[1];
  const float* Wq = (const float*)d_in[2];
  const float* bq = (const float*)d_in[3];
  const float* Wk = (const float*)d_in[4];
  // d_in[5] = bk cancels in softmax (row-constant)
  const float* Wv = (const float*)d_in[6];
  const float* bv = (const float*)d_in[7];
  const float* Wp = (const float*)d_in[8];
  const float* bp = (const float*)d_in[9];
  float* out = (float*)d_out;

  char* ws = (char*)d_ws;
  size_t off = 0;
  auto carve = [&](size_t bytes){ void* p = ws + off; off += (bytes + 255) & ~(size_t)255; return p; };
  short* t1b = (short*)carve(8L*1024*768*2);
  short* t2b = (short*)carve(8L*1024*768*2);
  short* WqH = (short*)carve(3L*768*768*2);       // plain fp16 [h][in][out]
  short* WkH = (short*)carve(3L*768*768*2);
  short* WvT = (short*)carve(3L*768*768*2);
  short* WpT = (short*)carve(768L*2304*2);
  short* Mt  = (short*)carve(3L*768*768*2);       // (Wq Wk^T)^T per head, fp16 [d'][d]
  short* Gb  = (short*)carve(3L*8192*768*2);      // G' = t1*M + w
  short* Vtb = (short*)carve(3L*8*768*1024*2);    // [hb][e][lk]
  short* Pb  = (short*)carve(24L*1024*1024*2);    // [hb][q][c]
  float* Mx  = (float*)carve(24L*8*1024*4);       // [hb*8+ct][q]
  float* Lx  = (float*)carve(24L*8*1024*4);
  float* wvb = (float*)carve(3L*768*4);           // w = Wk bq
  short* multib = Gb;   // alias: Gb dead after qk_exp; multi written by pv, read by gemm_out

  cvt2_f16_kernel<<<12288, 256, 0, stream>>>(t1, t2, t1b, t2b, 1572864);
  cvt2_f16_kernel<<<3456, 256, 0, stream>>>(Wq, Wk, WqH, WkH, 442368);
  transpose2_kernel<<<dim3(24,72,2), dim3(32,8), 0, stream>>>(Wv, Wp, WvT, WpT);
  vvec_kernel<<<dim3(3,8), 256, 0, stream>>>(Wk, bq, wvb);
  gemm_m_kernel<<<dim3(6,6,3), 256, 0, stream>>>(WqH, WkH, Mt);
  gemm_gv_kernel<<<dim3(64,6,6), 256, 0, stream>>>(t1b, t2b, Mt, WvT, wvb, bv, Gb, Vtb);
  qk_exp_kernel<<<1536, 256, 0, stream>>>(Gb, t2b, Pb, Mx, Lx);
  pv_kernel<<<1152, 256, 0, stream>>>(Pb, Vtb, Mx, Lx, multib);
  gemm_out_kernel<<<dim3(64,6,1), 256, 0, stream>>>(multib, WpT, bp, out);
}